// Round 10
// baseline (7599.412 us; speedup 1.0000x reference)
//
#include <hip/hip_runtime.h>

#define ANG 9
#define HH 96
#define BB 2
#define PLANE_F (81*HH*HH)  // 746496 per channel (81 views x 96x96)
#define PLANE_A (HH*HH)     // 9216
#define NBLK_FEAT 1458      // BB*81*9 blocks (each: 256 threads, 4-row strips)
#define INV_NBIG   (1.0f / 1492992.0f)
#define INV_NSMALL (1.0f / 18432.0f)
#define SCSTRIDE 192

// ===== last-block arrival: release fence + counter; returns 1 for the last block =====
__device__ __forceinline__ int bn_arrive(unsigned* __restrict__ cnt, unsigned nblk, int tid) {
  __shared__ int flag;
  __threadfence();                                  // release: own stores -> coherence point
  __syncthreads();
  if (tid == 0) {
    unsigned old = atomicAdd(cnt, 1u);              // device-scope
    flag = (old == nblk - 1u) ? 1 : 0;
  }
  __syncthreads();
  if (flag) __threadfence();                        // acquire: invalidate stale cache
  return flag;
}

// ===== feat-stage finish: reduce [a*1458+k] partials -> SC/SH (7 ch) =====
__device__ __forceinline__ void feat_finish(const float* __restrict__ psum,
    const float* __restrict__ psq, const float* __restrict__ g, const float* __restrict__ bb,
    float* __restrict__ sc, float* __restrict__ sh, int tid) {
  __shared__ float redf[4][14];
  #pragma unroll 1
  for (int a = 0; a < 14; a++) {
    const float* src = (a < 7) ? (psum + a * NBLK_FEAT) : (psq + (a - 7) * NBLK_FEAT);
    float v = 0.f;
    for (int k = tid; k < NBLK_FEAT; k += 256) v += src[k];
    #pragma unroll
    for (int off = 32; off > 0; off >>= 1) v += __shfl_down(v, off);
    if ((tid & 63) == 0) redf[tid >> 6][a] = v;
  }
  __syncthreads();
  if (tid < 7) {
    float S = redf[0][tid] + redf[1][tid] + redf[2][tid] + redf[3][tid];
    float Q = redf[0][tid+7] + redf[1][tid+7] + redf[2][tid+7] + redf[3][tid+7];
    float mean = S * INV_NBIG;
    float var = fmaxf(Q * INV_NBIG - mean * mean, 0.f);
    float scale = g[tid] / sqrtf(var + 1e-5f);
    sc[tid] = scale; sh[tid] = bb[tid] - mean * scale;
  }
}

// ===== agg-stage finish: reduce [c*72+k] partials -> SC/SH (C ch) =====
__device__ __forceinline__ void agg_finish(const float* __restrict__ dps,
    const float* __restrict__ dpq, const float* __restrict__ g, const float* __restrict__ bb,
    float* __restrict__ sc, float* __restrict__ sh, int tid, int C) {
  if (tid < C) {
    float S = 0.f, Q = 0.f;
    for (int k = 0; k < 72; k++) { S += dps[tid * 72 + k]; Q += dpq[tid * 72 + k]; }
    float mean = S * INV_NSMALL;
    float var = fmaxf(Q * INV_NSMALL - mean * mean, 0.f);
    float scale = g[tid] / sqrtf(var + 1e-5f);
    sc[tid] = scale; sh[tid] = bb[tid] - mean * scale;
  }
}

// ===== weight prep: BuildCost shuffle + pointwise transposes, one dispatch =====
__global__ __launch_bounds__(256) void k_wprep(const float* __restrict__ bcw,
    const float* __restrict__ a0pw, const float* __restrict__ ampw, const float* __restrict__ lpw,
    float* __restrict__ wt, float* __restrict__ wpt) {
  int k = blockIdx.x * 256 + threadIdx.x;
  if (k < 81648) {
    int o = k & 15; int rest = k >> 4;
    int r81 = rest % 81; int gc = rest / 81;
    int c = gc % 7, g = gc / 7;
    wt[k] = bcw[((g * 16 + o) * 7 + c) * 81 + r81];
    return;
  }
  int t = k - 81648;
  if (t < 25920) {                                   // a0pw [180][144] -> [c][o]
    int c = t / 180, o = t % 180;
    wpt[t] = a0pw[o * 144 + c];
  } else if (t < 25920 + 129600) {                   // ampw [m][180][180] -> [m][c][o]
    int t2 = t - 25920;
    int m = t2 / 32400, r = t2 % 32400;
    int c = r / 180, o = r % 180;
    wpt[t] = ampw[m * 32400 + o * 180 + c];
  } else if (t < 25920 + 129600 + 1620) {            // lpw [9][180] -> [c][o]
    int t2 = t - 25920 - 129600;
    int c = t2 / 9, o = t2 % 9;
    wpt[t] = lpw[o * 180 + c];
  }
}

// ===== feature conv0: 1->7 from raw x + fused stats + last-block BN-final =====
__global__ __launch_bounds__(256) void k_featconv0(const float* __restrict__ x,
    const float* __restrict__ w, float* __restrict__ out,
    float* __restrict__ psum, float* __restrict__ psq,
    const float* __restrict__ g, const float* __restrict__ bb,
    float* __restrict__ sc_out, float* __restrict__ sh_out, unsigned* __restrict__ cnt) {
  int blk = blockIdx.x, tid = threadIdx.x;
  int view = blk / 9, q = blk % 9;
  int b = view / 81, uv = view % 81;
  int u = uv / 9, v = uv % 9;
  int widx = q * 256 + tid;
  int j = widx % HH, i0 = (widx / HH) * 4;
  const float* bx = x + (size_t)b * PLANE_F + (u * HH) * 864 + v * HH;
  int off[6][3]; float m[6][3];
  #pragma unroll
  for (int r6 = 0; r6 < 6; r6++) {
    int ii = i0 + r6 - 1;
    float mi = ((unsigned)ii < 96u) ? 1.f : 0.f;
    int iic = min(max(ii, 0), 95);
    #pragma unroll
    for (int dx = 0; dx < 3; dx++) {
      int jj = j + dx - 1;
      float mj = ((unsigned)jj < 96u) ? 1.f : 0.f;
      int jjc = min(max(jj, 0), 95);
      off[r6][dx] = iic * 864 + jjc;
      m[r6][dx] = mi * mj;
    }
  }
  float win[6][3];
  #pragma unroll
  for (int r6 = 0; r6 < 6; r6++)
    #pragma unroll
    for (int dx = 0; dx < 3; dx++)
      win[r6][dx] = bx[off[r6][dx]] * m[r6][dx];
  float acc[4][7];
  #pragma unroll
  for (int px = 0; px < 4; px++)
    #pragma unroll
    for (int o = 0; o < 7; o++) acc[px][o] = 0.f;
  #pragma unroll
  for (int o = 0; o < 7; o++) {
    const float* wc = w + o * 9;
    #pragma unroll
    for (int ky = 0; ky < 3; ky++)
      #pragma unroll
      for (int kx = 0; kx < 3; kx++) {
        float wv = wc[ky * 3 + kx];
        #pragma unroll
        for (int px = 0; px < 4; px++)
          acc[px][o] = fmaf(win[px + ky][kx], wv, acc[px][o]);
      }
  }
  #pragma unroll
  for (int o = 0; o < 7; o++) {
    float* op = out + ((size_t)(b * 7 + o)) * PLANE_F + uv * PLANE_A + i0 * HH + j;
    #pragma unroll
    for (int px = 0; px < 4; px++) op[px * HH] = acc[px][o];
  }
  float sv[7], qv[7];
  #pragma unroll
  for (int o = 0; o < 7; o++) {
    sv[o] = acc[0][o] + acc[1][o] + acc[2][o] + acc[3][o];
    qv[o] = acc[0][o]*acc[0][o] + acc[1][o]*acc[1][o] + acc[2][o]*acc[2][o] + acc[3][o]*acc[3][o];
  }
  #pragma unroll
  for (int off2 = 32; off2 > 0; off2 >>= 1)
    #pragma unroll
    for (int o = 0; o < 7; o++) { sv[o] += __shfl_down(sv[o], off2); qv[o] += __shfl_down(qv[o], off2); }
  __shared__ float red[4][14];
  int wave = tid >> 6, lane = tid & 63;
  if (lane == 0) {
    #pragma unroll
    for (int o = 0; o < 7; o++) { red[wave][o] = sv[o]; red[wave][7 + o] = qv[o]; }
  }
  __syncthreads();
  if (tid < 14) {
    float t4 = red[0][tid] + red[1][tid] + red[2][tid] + red[3][tid];
    if (tid < 7) psum[tid * NBLK_FEAT + blk] = t4;
    else         psq[(tid - 7) * NBLK_FEAT + blk] = t4;
  }
  if (bn_arrive(cnt, NBLK_FEAT, tid))
    feat_finish(psum, psq, g, bb, sc_out, sh_out, tid);
}

// ===== feature conv: 7->7, fused BN+ReLU + stats + last-block BN-final =====
__global__ __launch_bounds__(256) void k_featconv4(const float* __restrict__ in,
    const float* __restrict__ w, const float* __restrict__ sc, const float* __restrict__ sh,
    float* __restrict__ out, float* __restrict__ psum, float* __restrict__ psq,
    const float* __restrict__ g, const float* __restrict__ bb,
    float* __restrict__ sc_out, float* __restrict__ sh_out, unsigned* __restrict__ cnt) {
  int blk = blockIdx.x, tid = threadIdx.x;
  int view = blk / 9, q = blk % 9;
  int b = view / 81, uv = view % 81;
  int widx = q * 256 + tid;
  int j = widx % HH, i0 = (widx / HH) * 4;
  int off[6][3]; float m[6][3];
  #pragma unroll
  for (int r6 = 0; r6 < 6; r6++) {
    int ii = i0 + r6 - 1;
    float mi = ((unsigned)ii < 96u) ? 1.f : 0.f;
    int iic = min(max(ii, 0), 95);
    #pragma unroll
    for (int dx = 0; dx < 3; dx++) {
      int jj = j + dx - 1;
      float mj = ((unsigned)jj < 96u) ? 1.f : 0.f;
      int jjc = min(max(jj, 0), 95);
      off[r6][dx] = iic * HH + jjc;
      m[r6][dx] = mi * mj;
    }
  }
  float acc[4][7];
  #pragma unroll
  for (int px = 0; px < 4; px++)
    #pragma unroll
    for (int o = 0; o < 7; o++) acc[px][o] = 0.f;
  const float* ipbase = in + ((size_t)(b * 7)) * PLANE_F + uv * PLANE_A;
  float pre[6][3];
  #pragma unroll
  for (int r6 = 0; r6 < 6; r6++)
    #pragma unroll
    for (int dx = 0; dx < 3; dx++)
      pre[r6][dx] = ipbase[off[r6][dx]];
  #pragma unroll 1
  for (int c = 0; c < 7; c++) {
    float s = sc[c], h2 = sh[c];
    float win[6][3];
    #pragma unroll
    for (int r6 = 0; r6 < 6; r6++)
      #pragma unroll
      for (int dx = 0; dx < 3; dx++)
        win[r6][dx] = fmaxf(fmaf(pre[r6][dx], s, h2), 0.f) * m[r6][dx];
    if (c < 6) {
      const float* ipn = ipbase + (size_t)(c + 1) * PLANE_F;
      #pragma unroll
      for (int r6 = 0; r6 < 6; r6++)
        #pragma unroll
        for (int dx = 0; dx < 3; dx++)
          pre[r6][dx] = ipn[off[r6][dx]];
    }
    #pragma unroll
    for (int o = 0; o < 7; o++) {
      const float* wc = w + (o * 7 + c) * 9;
      #pragma unroll
      for (int ky = 0; ky < 3; ky++)
        #pragma unroll
        for (int kx = 0; kx < 3; kx++) {
          float wv = wc[ky * 3 + kx];
          #pragma unroll
          for (int px = 0; px < 4; px++)
            acc[px][o] = fmaf(win[px + ky][kx], wv, acc[px][o]);
        }
    }
  }
  #pragma unroll
  for (int o = 0; o < 7; o++) {
    float* op = out + ((size_t)(b * 7 + o)) * PLANE_F + uv * PLANE_A + i0 * HH + j;
    #pragma unroll
    for (int px = 0; px < 4; px++) op[px * HH] = acc[px][o];
  }
  float sv[7], qv[7];
  #pragma unroll
  for (int o = 0; o < 7; o++) {
    sv[o] = acc[0][o] + acc[1][o] + acc[2][o] + acc[3][o];
    qv[o] = acc[0][o]*acc[0][o] + acc[1][o]*acc[1][o] + acc[2][o]*acc[2][o] + acc[3][o]*acc[3][o];
  }
  #pragma unroll
  for (int off2 = 32; off2 > 0; off2 >>= 1)
    #pragma unroll
    for (int o = 0; o < 7; o++) { sv[o] += __shfl_down(sv[o], off2); qv[o] += __shfl_down(qv[o], off2); }
  __shared__ float red[4][14];
  int wave = tid >> 6, lane = tid & 63;
  if (lane == 0) {
    #pragma unroll
    for (int o = 0; o < 7; o++) { red[wave][o] = sv[o]; red[wave][7 + o] = qv[o]; }
  }
  __syncthreads();
  if (tid < 14) {
    float t4 = red[0][tid] + red[1][tid] + red[2][tid] + red[3][tid];
    if (tid < 7) psum[tid * NBLK_FEAT + blk] = t4;
    else         psq[(tid - 7) * NBLK_FEAT + blk] = t4;
  }
  if (bn_arrive(cnt, NBLK_FEAT, tid))
    feat_finish(psum, psq, g, bb, sc_out, sh_out, tid);
}

// ===== BuildCost helper: branchless clamped 9-tap load (R6-proven) =====
__device__ __forceinline__ void bc_load(const float* __restrict__ F, int b, int c, int u,
    int d, int i, int j, float* raw, float* msk) {
  const float* Fc = F + ((size_t)(b * 7 + c)) * PLANE_F + (u * 9) * PLANE_A;
  int ii = i + d * (4 - u);
  float mi = ((unsigned)ii < 96u) ? 1.f : 0.f;
  int iic = min(max(ii, 0), 95);
  const float* Frow = Fc + iic * HH;
  #pragma unroll
  for (int v = 0; v < 9; v++) {
    int jj = j + d * (4 - v);
    float mj = ((unsigned)jj < 96u) ? 1.f : 0.f;
    int jjc = min(max(jj, 0), 95);
    raw[v] = Frow[v * PLANE_A + jjc];
    msk[v] = mi * mj;
  }
}

// ===== BuildCost: 8-o split, SGPR weights, prefetched branchless loads (R6) =====
__global__ __launch_bounds__(256) void k_buildcost(const float* __restrict__ F,
    const float* __restrict__ sc, const float* __restrict__ sh,
    const float* __restrict__ wt, float* __restrict__ cv) {
  int gg = blockIdx.x, b = blockIdx.z, tid = threadIdx.x;
  int g = gg >> 1, half = gg & 1;
  int d = g - 4;
  bool flip = d > 0;
  int p = blockIdx.y * 256 + tid;
  int i = p / HH, j = p % HH;
  float acc[8];
  #pragma unroll
  for (int o = 0; o < 8; o++) acc[o] = 0.f;
  float raw[9], msk[9];
  bc_load(F, b, 0, 0, d, i, j, raw, msk);
  #pragma unroll 1
  for (int cu = 0; cu < 63; cu++) {
    int c = cu / 9, u = cu - c * 9;
    float cr[9], cm[9];
    #pragma unroll
    for (int v = 0; v < 9; v++) { cr[v] = raw[v]; cm[v] = msk[v]; }
    if (cu + 1 < 63) {
      int cn = (cu + 1) / 9, un = (cu + 1) - cn * 9;
      bc_load(F, b, cn, un, d, i, j, raw, msk);
    }
    float s = sc[c], h2 = sh[c];
    int uw = flip ? 8 - u : u;
    const float* wbase = wt + ((size_t)((g * 7 + c) * 81 + uw * 9)) * 16 + half * 8;
    #pragma unroll
    for (int v = 0; v < 9; v++) {
      float a = fmaxf(fmaf(cr[v], s, h2), 0.f) * cm[v];
      int vw = flip ? 8 - v : v;
      const float* wp = wbase + vw * 16;            // uniform -> s_load
      #pragma unroll
      for (int o = 0; o < 8; o++) acc[o] = fmaf(wp[o], a, acc[o]);
    }
  }
  size_t cvb = ((size_t)(b * 144 + g * 16 + half * 8)) * PLANE_A + p;
  #pragma unroll
  for (int o = 0; o < 8; o++) cv[cvb + o * PLANE_A] = acc[o];
}

// ===== depthwise 3x3: fused input BN+ReLU + stats + last-block BN-final =====
template<bool AFF>
__global__ __launch_bounds__(256) void k_dwconv(const float* __restrict__ in,
    const float* __restrict__ w, const float* __restrict__ isc, const float* __restrict__ ish,
    const float* __restrict__ g, const float* __restrict__ bbias,
    float* __restrict__ out, float* __restrict__ dps, float* __restrict__ dpq,
    float* __restrict__ sc_out, float* __restrict__ sh_out, unsigned* __restrict__ cnt, int C) {
  int blk = blockIdx.x, tid = threadIdx.x;
  int t = blk * 256 + tid;
  int j = t % HH; int r = t / HH; int i = r % HH; r /= HH; int c = r % C; int b = r / C;
  float s  = AFF ? isc[c] : 1.f;
  float h2 = AFF ? ish[c] : 0.f;
  const float* ip = in + ((size_t)(b * C + c)) * PLANE_A;
  float acc = 0.f;
  #pragma unroll
  for (int ky = 0; ky < 3; ky++) {
    int ii = i + ky - 1;
    if ((unsigned)ii >= (unsigned)HH) continue;
    #pragma unroll
    for (int kx = 0; kx < 3; kx++) {
      int jj = j + kx - 1;
      if ((unsigned)jj >= (unsigned)HH) continue;
      float v = ip[ii * HH + jj];
      if (AFF) v = fmaxf(fmaf(v, s, h2), 0.f);
      acc = fmaf(w[c * 9 + ky * 3 + kx], v, acc);
    }
  }
  out[t] = acc;
  float sv = acc, qv = acc * acc;
  #pragma unroll
  for (int off = 32; off > 0; off >>= 1) { sv += __shfl_down(sv, off); qv += __shfl_down(qv, off); }
  __shared__ float red[4][2];
  int wave = tid >> 6, lane = tid & 63;
  if (lane == 0) { red[wave][0] = sv; red[wave][1] = qv; }
  __syncthreads();
  if (tid == 0) {
    float S = red[0][0] + red[1][0] + red[2][0] + red[3][0];
    float Q = red[0][1] + red[1][1] + red[2][1] + red[3][1];
    int chunk = blk % 36; int rr = blk / 36; int c2 = rr % C; int b2 = rr / C;
    dps[c2 * 72 + b2 * 36 + chunk] = S;
    dpq[c2 * 72 + b2 * 36 + chunk] = Q;
  }
  if (bn_arrive(cnt, gridDim.x, tid))
    agg_finish(dps, dpq, g, bbias, sc_out, sh_out, tid, C);
}

// ===== pointwise conv: 18 out/thread, transposed weights + last-block BN-final =====
// grid (10, 72): x = output group (18 outputs), y = position block
template<int K>
__global__ __launch_bounds__(256) void k_pwconv(const float* __restrict__ in,
    const float* __restrict__ sc, const float* __restrict__ sh,
    const float* __restrict__ wpt, float* __restrict__ out,
    float* __restrict__ pps, float* __restrict__ ppq,
    const float* __restrict__ g, const float* __restrict__ bbias,
    float* __restrict__ sc_out, float* __restrict__ sh_out, unsigned* __restrict__ cnt) {
  int tid = threadIdx.x;
  int posblk = blockIdx.y;
  int p = posblk * 256 + tid;
  int b = p / PLANE_A, pp = p - b * PLANE_A;
  int obase = blockIdx.x * 18;
  float acc[18];
  #pragma unroll
  for (int o = 0; o < 18; o++) acc[o] = 0.f;
  const float* ib = in + (size_t)b * K * PLANE_A + pp;
  float xn[4];
  #pragma unroll
  for (int q2 = 0; q2 < 4; q2++) xn[q2] = ib[(size_t)q2 * PLANE_A];
  #pragma unroll 1
  for (int c0 = 0; c0 < K; c0 += 4) {
    float xv[4];
    #pragma unroll
    for (int q2 = 0; q2 < 4; q2++) xv[q2] = xn[q2];
    if (c0 + 4 < K) {
      #pragma unroll
      for (int q2 = 0; q2 < 4; q2++) xn[q2] = ib[(size_t)(c0 + 4 + q2) * PLANE_A];
    }
    #pragma unroll
    for (int q2 = 0; q2 < 4; q2++) {
      int c = c0 + q2;
      float v = fmaxf(fmaf(xv[q2], sc[c], sh[c]), 0.f);
      const float* wc = wpt + (size_t)c * 180 + obase;  // uniform, contiguous x18
      #pragma unroll
      for (int o = 0; o < 18; o++)
        acc[o] = fmaf(wc[o], v, acc[o]);
    }
  }
  #pragma unroll
  for (int o = 0; o < 18; o++)
    out[((size_t)(b * 180 + obase + o)) * PLANE_A + pp] = acc[o];
  __shared__ float rs[4][18], rq[4][18];
  int wave = tid >> 6, lane = tid & 63;
  #pragma unroll
  for (int o = 0; o < 18; o++) {
    float s = acc[o], q = acc[o] * acc[o];
    #pragma unroll
    for (int off = 32; off > 0; off >>= 1) { s += __shfl_down(s, off); q += __shfl_down(q, off); }
    if (lane == 0) { rs[wave][o] = s; rq[wave][o] = q; }
  }
  __syncthreads();
  if (tid < 18)
    pps[(obase + tid) * 72 + posblk] = rs[0][tid] + rs[1][tid] + rs[2][tid] + rs[3][tid];
  else if (tid < 36) {
    int o = tid - 18;
    ppq[(obase + o) * 72 + posblk] = rq[0][o] + rq[1][o] + rq[2][o] + rq[3][o];
  }
  if (bn_arrive(cnt, gridDim.x * gridDim.y, tid))
    agg_finish(pps, ppq, g, bbias, sc_out, sh_out, tid, 180);
}

// ===== final: 1x1 conv 180->9 (transposed wt) + softmax + expectation =====
__global__ __launch_bounds__(256) void k_final(const float* __restrict__ in,
    const float* __restrict__ sc, const float* __restrict__ sh,
    const float* __restrict__ wpt, float* __restrict__ out) {
  int tid = threadIdx.x;
  int t = blockIdx.x * 256 + tid;
  int b = t / PLANE_A, p = t - b * PLANE_A;
  const float* ib = in + (size_t)b * 180 * PLANE_A + p;
  float acc[9];
  #pragma unroll
  for (int o = 0; o < 9; o++) acc[o] = 0.f;
  float xn[4];
  #pragma unroll
  for (int q2 = 0; q2 < 4; q2++) xn[q2] = ib[(size_t)q2 * PLANE_A];
  #pragma unroll 1
  for (int c0 = 0; c0 < 180; c0 += 4) {
    float xv[4];
    #pragma unroll
    for (int q2 = 0; q2 < 4; q2++) xv[q2] = xn[q2];
    if (c0 + 4 < 180) {
      #pragma unroll
      for (int q2 = 0; q2 < 4; q2++) xn[q2] = ib[(size_t)(c0 + 4 + q2) * PLANE_A];
    }
    #pragma unroll
    for (int q2 = 0; q2 < 4; q2++) {
      int c = c0 + q2;
      float v = fmaxf(fmaf(xv[q2], sc[c], sh[c]), 0.f);
      const float* wc = wpt + (size_t)c * 9;        // uniform, contiguous x9
      #pragma unroll
      for (int o = 0; o < 9; o++) acc[o] = fmaf(wc[o], v, acc[o]);
    }
  }
  float m = acc[0];
  #pragma unroll
  for (int o = 1; o < 9; o++) m = fmaxf(m, acc[o]);
  float se = 0.f, num = 0.f;
  #pragma unroll
  for (int o = 0; o < 9; o++) {
    float e = expf(acc[o] - m);
    se += e;
    num += (float)(o - 4) * e;
  }
  out[t] = num / se;
}

extern "C" void kernel_launch(void* const* d_in, const int* in_sizes, int n_in,
                              void* d_out, int out_size, void* d_ws, size_t ws_size,
                              hipStream_t stream) {
  const float* x    = (const float*)d_in[0];
  const float* fw0  = (const float*)d_in[1];
  const float* fg0  = (const float*)d_in[2];
  const float* fb0  = (const float*)d_in[3];
  const float* fw   = (const float*)d_in[4];
  const float* fg   = (const float*)d_in[5];
  const float* fb   = (const float*)d_in[6];
  const float* bcw  = (const float*)d_in[7];
  const float* a0dw = (const float*)d_in[8];
  const float* a0dg = (const float*)d_in[9];
  const float* a0db = (const float*)d_in[10];
  const float* a0pw = (const float*)d_in[11];
  const float* a0pg = (const float*)d_in[12];
  const float* a0pb = (const float*)d_in[13];
  const float* amdw = (const float*)d_in[14];
  const float* amdg = (const float*)d_in[15];
  const float* amdb = (const float*)d_in[16];
  const float* ampw = (const float*)d_in[17];
  const float* ampg = (const float*)d_in[18];
  const float* ampb = (const float*)d_in[19];
  const float* ldw  = (const float*)d_in[20];
  const float* ldg  = (const float*)d_in[21];
  const float* ldb  = (const float*)d_in[22];
  const float* lpw  = (const float*)d_in[23];
  float* outp = (float*)d_out;

  float* FA    = (float*)d_ws;
  float* FB    = FA + (size_t)BB * 7 * PLANE_F;
  float* CV    = FB + (size_t)BB * 7 * PLANE_F;
  float* GA    = CV + (size_t)BB * 144 * PLANE_A;
  float* GB    = GA + (size_t)BB * 180 * PLANE_A;
  float* PSUM  = GB + (size_t)BB * 180 * PLANE_A;   // 7*1458 / 180*72 both fit
  float* PSQ   = PSUM + 180 * 288;
  float* SCS   = PSQ + 180 * 288;                    // 18 stages x 192
  float* SHS   = SCS + 18 * SCSTRIDE;
  float* WT    = SHS + 18 * SCSTRIDE;                // 81648
  float* WPT   = WT + 81648;                         // 157140
  float* WPT_A0 = WPT;                               // [144][180]
  float* WPT_AM = WPT + 25920;                       // 4 x [180][180]
  float* WPT_L  = WPT + 25920 + 129600;              // [180][9]
  unsigned* CNT = (unsigned*)(WPT + 157140);         // 18 counters

  // zero stage counters (graph-capturable memset node)
  hipMemsetAsync(CNT, 0, 18 * sizeof(unsigned), stream);

  // weight prep (BuildCost shuffle + pointwise transposes), one dispatch
  k_wprep<<<(238788 + 255) / 256, 256, 0, stream>>>(bcw, a0pw, ampw, lpw, WT, WPT);

  // feature extraction; BN-final fused into producer's last block
  k_featconv0<<<NBLK_FEAT, 256, 0, stream>>>(x, fw0, FA, PSUM, PSQ,
      fg0, fb0, SCS + 0 * SCSTRIDE, SHS + 0 * SCSTRIDE, CNT + 0);

  float* cur = FA; float* nxt = FB;
  for (int i = 0; i < 6; i++) {
    k_featconv4<<<NBLK_FEAT, 256, 0, stream>>>(cur, fw + i * 441,
        SCS + i * SCSTRIDE, SHS + i * SCSTRIDE, nxt, PSUM, PSQ,
        fg + i * 7, fb + i * 7,
        SCS + (i + 1) * SCSTRIDE, SHS + (i + 1) * SCSTRIDE, CNT + 1 + i);
    float* tmp = cur; cur = nxt; nxt = tmp;
  }

  // BuildCost consumes stage-6 stats
  k_buildcost<<<dim3(18, 36, 2), 256, 0, stream>>>(cur,
      SCS + 6 * SCSTRIDE, SHS + 6 * SCSTRIDE, WT, CV);

  // aggregation: BN-final fused into each producer's last block
  k_dwconv<false><<<BB * 144 * 36, 256, 0, stream>>>(CV, a0dw, nullptr, nullptr,
      a0dg, a0db, GA, PSUM, PSQ,
      SCS + 7 * SCSTRIDE, SHS + 7 * SCSTRIDE, CNT + 7, 144);
  k_pwconv<144><<<dim3(10, 72), 256, 0, stream>>>(GA,
      SCS + 7 * SCSTRIDE, SHS + 7 * SCSTRIDE, WPT_A0, GB, PSUM, PSQ,
      a0pg, a0pb, SCS + 8 * SCSTRIDE, SHS + 8 * SCSTRIDE, CNT + 8);

  for (int m = 0; m < 4; m++) {
    k_dwconv<true><<<BB * 180 * 36, 256, 0, stream>>>(GB, amdw + m * 1620,
        SCS + (8 + 2 * m) * SCSTRIDE, SHS + (8 + 2 * m) * SCSTRIDE,
        amdg + m * 180, amdb + m * 180, GA, PSUM, PSQ,
        SCS + (9 + 2 * m) * SCSTRIDE, SHS + (9 + 2 * m) * SCSTRIDE, CNT + 9 + 2 * m, 180);
    k_pwconv<180><<<dim3(10, 72), 256, 0, stream>>>(GA,
        SCS + (9 + 2 * m) * SCSTRIDE, SHS + (9 + 2 * m) * SCSTRIDE,
        WPT_AM + m * 32400, GB, PSUM, PSQ,
        ampg + m * 180, ampb + m * 180,
        SCS + (10 + 2 * m) * SCSTRIDE, SHS + (10 + 2 * m) * SCSTRIDE, CNT + 10 + 2 * m);
  }

  k_dwconv<true><<<BB * 180 * 36, 256, 0, stream>>>(GB, ldw,
      SCS + 16 * SCSTRIDE, SHS + 16 * SCSTRIDE,
      ldg, ldb, GA, PSUM, PSQ,
      SCS + 17 * SCSTRIDE, SHS + 17 * SCSTRIDE, CNT + 17, 180);

  k_final<<<72, 256, 0, stream>>>(GA, SCS + 17 * SCSTRIDE, SHS + 17 * SCSTRIDE, WPT_L, outp);
}

// Round 12
// 795.336 us; speedup vs baseline: 9.5550x; 9.5550x over previous
//
#include <hip/hip_runtime.h>

#define ANG 9
#define HH 96
#define BB 2
#define PLANE_F (81*HH*HH)  // 746496 per channel (81 views x 96x96)
#define PLANE_A (HH*HH)     // 9216
#define NBLK_FEAT 1458      // BB*81*9 blocks (each: 256 threads, 4-row strips)

// ===== generic BN-final: reduce per-block partials -> scale/shift =====
__global__ __launch_bounds__(256) void k_bnfinal(const float* __restrict__ psum,
    const float* __restrict__ psq, const float* __restrict__ g, const float* __restrict__ bbias,
    float* __restrict__ sc, float* __restrict__ sh, int NB, float invN) {
  int c = blockIdx.x, tid = threadIdx.x;
  float s = 0.f, q = 0.f;
  for (int k = tid; k < NB; k += 256) { s += psum[c * NB + k]; q += psq[c * NB + k]; }
  __shared__ float ss[256], qq[256];
  ss[tid] = s; qq[tid] = q;
  __syncthreads();
  for (int st = 128; st > 0; st >>= 1) {
    if (tid < st) { ss[tid] += ss[tid + st]; qq[tid] += qq[tid + st]; }
    __syncthreads();
  }
  if (tid == 0) {
    float mean = ss[0] * invN;
    float var = fmaxf(qq[0] * invN - mean * mean, 0.f);
    float scale = g[c] / sqrtf(var + 1e-5f);
    sc[c] = scale; sh[c] = bbias[c] - mean * scale;
  }
}

// ===== weight prep: BuildCost shuffle + pointwise transposes, one dispatch =====
// wt: WT[((g*7+c)*81 + u*9+v)*16 + o]  (81648)
// wpt: [a0pw^T (144x180) | 4x ampw^T (180x180) | lpw^T (180x9)]  (157140)
__global__ __launch_bounds__(256) void k_wprep(const float* __restrict__ bcw,
    const float* __restrict__ a0pw, const float* __restrict__ ampw, const float* __restrict__ lpw,
    float* __restrict__ wt, float* __restrict__ wpt) {
  int k = blockIdx.x * 256 + threadIdx.x;
  if (k < 81648) {
    int o = k & 15; int rest = k >> 4;
    int r81 = rest % 81; int gc = rest / 81;
    int c = gc % 7, g = gc / 7;
    wt[k] = bcw[((g * 16 + o) * 7 + c) * 81 + r81];
    return;
  }
  int t = k - 81648;
  if (t < 25920) {                                   // a0pw [180][144] -> [c][o]
    int c = t / 180, o = t % 180;
    wpt[t] = a0pw[o * 144 + c];
  } else if (t < 25920 + 129600) {                   // ampw [m][180][180] -> [m][c][o]
    int t2 = t - 25920;
    int m = t2 / 32400, r = t2 % 32400;
    int c = r / 180, o = r % 180;
    wpt[t] = ampw[m * 32400 + o * 180 + c];
  } else if (t < 25920 + 129600 + 1620) {            // lpw [9][180] -> [c][o]
    int t2 = t - 25920 - 129600;
    int c = t2 / 9, o = t2 % 9;
    wpt[t] = lpw[o * 180 + c];
  }
}

// ===== feature conv0: 1->7 from raw x, branchless clamped window, fused stats =====
__global__ __launch_bounds__(256) void k_featconv0(const float* __restrict__ x,
    const float* __restrict__ w, float* __restrict__ out,
    float* __restrict__ psum, float* __restrict__ psq) {
  int blk = blockIdx.x, tid = threadIdx.x;
  int view = blk / 9, q = blk % 9;
  int b = view / 81, uv = view % 81;
  int u = uv / 9, v = uv % 9;
  int widx = q * 256 + tid;
  int j = widx % HH, i0 = (widx / HH) * 4;
  const float* bx = x + (size_t)b * PLANE_F + (u * HH) * 864 + v * HH;
  int off[6][3]; float m[6][3];
  #pragma unroll
  for (int r6 = 0; r6 < 6; r6++) {
    int ii = i0 + r6 - 1;
    float mi = ((unsigned)ii < 96u) ? 1.f : 0.f;
    int iic = min(max(ii, 0), 95);
    #pragma unroll
    for (int dx = 0; dx < 3; dx++) {
      int jj = j + dx - 1;
      float mj = ((unsigned)jj < 96u) ? 1.f : 0.f;
      int jjc = min(max(jj, 0), 95);
      off[r6][dx] = iic * 864 + jjc;
      m[r6][dx] = mi * mj;
    }
  }
  float win[6][3];
  #pragma unroll
  for (int r6 = 0; r6 < 6; r6++)
    #pragma unroll
    for (int dx = 0; dx < 3; dx++)
      win[r6][dx] = bx[off[r6][dx]] * m[r6][dx];
  float acc[4][7];
  #pragma unroll
  for (int px = 0; px < 4; px++)
    #pragma unroll
    for (int o = 0; o < 7; o++) acc[px][o] = 0.f;
  #pragma unroll
  for (int o = 0; o < 7; o++) {
    const float* wc = w + o * 9;
    #pragma unroll
    for (int ky = 0; ky < 3; ky++)
      #pragma unroll
      for (int kx = 0; kx < 3; kx++) {
        float wv = wc[ky * 3 + kx];
        #pragma unroll
        for (int px = 0; px < 4; px++)
          acc[px][o] = fmaf(win[px + ky][kx], wv, acc[px][o]);
      }
  }
  #pragma unroll
  for (int o = 0; o < 7; o++) {
    float* op = out + ((size_t)(b * 7 + o)) * PLANE_F + uv * PLANE_A + i0 * HH + j;
    #pragma unroll
    for (int px = 0; px < 4; px++) op[px * HH] = acc[px][o];
  }
  float sv[7], qv[7];
  #pragma unroll
  for (int o = 0; o < 7; o++) {
    sv[o] = acc[0][o] + acc[1][o] + acc[2][o] + acc[3][o];
    qv[o] = acc[0][o]*acc[0][o] + acc[1][o]*acc[1][o] + acc[2][o]*acc[2][o] + acc[3][o]*acc[3][o];
  }
  #pragma unroll
  for (int off2 = 32; off2 > 0; off2 >>= 1)
    #pragma unroll
    for (int o = 0; o < 7; o++) { sv[o] += __shfl_down(sv[o], off2); qv[o] += __shfl_down(qv[o], off2); }
  __shared__ float red[4][14];
  int wave = tid >> 6, lane = tid & 63;
  if (lane == 0) {
    #pragma unroll
    for (int o = 0; o < 7; o++) { red[wave][o] = sv[o]; red[wave][7 + o] = qv[o]; }
  }
  __syncthreads();
  if (tid < 14) {
    float t4 = red[0][tid] + red[1][tid] + red[2][tid] + red[3][tid];
    if (tid < 7) psum[tid * NBLK_FEAT + blk] = t4;
    else         psq[(tid - 7) * NBLK_FEAT + blk] = t4;
  }
}

// ===== feature conv: 7->7, branchless window + channel prefetch, fused stats =====
__global__ __launch_bounds__(256) void k_featconv4(const float* __restrict__ in,
    const float* __restrict__ w, const float* __restrict__ sc, const float* __restrict__ sh,
    float* __restrict__ out, float* __restrict__ psum, float* __restrict__ psq) {
  int blk = blockIdx.x, tid = threadIdx.x;
  int view = blk / 9, q = blk % 9;
  int b = view / 81, uv = view % 81;
  int widx = q * 256 + tid;
  int j = widx % HH, i0 = (widx / HH) * 4;
  int off[6][3]; float m[6][3];
  #pragma unroll
  for (int r6 = 0; r6 < 6; r6++) {
    int ii = i0 + r6 - 1;
    float mi = ((unsigned)ii < 96u) ? 1.f : 0.f;
    int iic = min(max(ii, 0), 95);
    #pragma unroll
    for (int dx = 0; dx < 3; dx++) {
      int jj = j + dx - 1;
      float mj = ((unsigned)jj < 96u) ? 1.f : 0.f;
      int jjc = min(max(jj, 0), 95);
      off[r6][dx] = iic * HH + jjc;
      m[r6][dx] = mi * mj;
    }
  }
  float acc[4][7];
  #pragma unroll
  for (int px = 0; px < 4; px++)
    #pragma unroll
    for (int o = 0; o < 7; o++) acc[px][o] = 0.f;
  const float* ipbase = in + ((size_t)(b * 7)) * PLANE_F + uv * PLANE_A;
  float pre[6][3];
  #pragma unroll
  for (int r6 = 0; r6 < 6; r6++)
    #pragma unroll
    for (int dx = 0; dx < 3; dx++)
      pre[r6][dx] = ipbase[off[r6][dx]];
  #pragma unroll 1
  for (int c = 0; c < 7; c++) {
    float s = sc[c], h2 = sh[c];
    float win[6][3];
    #pragma unroll
    for (int r6 = 0; r6 < 6; r6++)
      #pragma unroll
      for (int dx = 0; dx < 3; dx++)
        win[r6][dx] = fmaxf(fmaf(pre[r6][dx], s, h2), 0.f) * m[r6][dx];
    if (c < 6) {
      const float* ipn = ipbase + (size_t)(c + 1) * PLANE_F;
      #pragma unroll
      for (int r6 = 0; r6 < 6; r6++)
        #pragma unroll
        for (int dx = 0; dx < 3; dx++)
          pre[r6][dx] = ipn[off[r6][dx]];
    }
    #pragma unroll
    for (int o = 0; o < 7; o++) {
      const float* wc = w + (o * 7 + c) * 9;
      #pragma unroll
      for (int ky = 0; ky < 3; ky++)
        #pragma unroll
        for (int kx = 0; kx < 3; kx++) {
          float wv = wc[ky * 3 + kx];
          #pragma unroll
          for (int px = 0; px < 4; px++)
            acc[px][o] = fmaf(win[px + ky][kx], wv, acc[px][o]);
        }
    }
  }
  #pragma unroll
  for (int o = 0; o < 7; o++) {
    float* op = out + ((size_t)(b * 7 + o)) * PLANE_F + uv * PLANE_A + i0 * HH + j;
    #pragma unroll
    for (int px = 0; px < 4; px++) op[px * HH] = acc[px][o];
  }
  float sv[7], qv[7];
  #pragma unroll
  for (int o = 0; o < 7; o++) {
    sv[o] = acc[0][o] + acc[1][o] + acc[2][o] + acc[3][o];
    qv[o] = acc[0][o]*acc[0][o] + acc[1][o]*acc[1][o] + acc[2][o]*acc[2][o] + acc[3][o]*acc[3][o];
  }
  #pragma unroll
  for (int off2 = 32; off2 > 0; off2 >>= 1)
    #pragma unroll
    for (int o = 0; o < 7; o++) { sv[o] += __shfl_down(sv[o], off2); qv[o] += __shfl_down(qv[o], off2); }
  __shared__ float red[4][14];
  int wave = tid >> 6, lane = tid & 63;
  if (lane == 0) {
    #pragma unroll
    for (int o = 0; o < 7; o++) { red[wave][o] = sv[o]; red[wave][7 + o] = qv[o]; }
  }
  __syncthreads();
  if (tid < 14) {
    float t4 = red[0][tid] + red[1][tid] + red[2][tid] + red[3][tid];
    if (tid < 7) psum[tid * NBLK_FEAT + blk] = t4;
    else         psq[(tid - 7) * NBLK_FEAT + blk] = t4;
  }
}

// ===== BuildCost helper: branchless clamped 9-tap load (R6-proven) =====
__device__ __forceinline__ void bc_load(const float* __restrict__ F, int b, int c, int u,
    int d, int i, int j, float* raw, float* msk) {
  const float* Fc = F + ((size_t)(b * 7 + c)) * PLANE_F + (u * 9) * PLANE_A;
  int ii = i + d * (4 - u);
  float mi = ((unsigned)ii < 96u) ? 1.f : 0.f;
  int iic = min(max(ii, 0), 95);
  const float* Frow = Fc + iic * HH;
  #pragma unroll
  for (int v = 0; v < 9; v++) {
    int jj = j + d * (4 - v);
    float mj = ((unsigned)jj < 96u) ? 1.f : 0.f;
    int jjc = min(max(jj, 0), 95);
    raw[v] = Frow[v * PLANE_A + jjc];
    msk[v] = mi * mj;
  }
}

// ===== BuildCost: 8-o split, SGPR weights, prefetched branchless loads (R6) =====
// grid (18, 36, 2): x = gg (g*2+half, fastest for L3 reuse), y = pos block, z = b
__global__ __launch_bounds__(256) void k_buildcost(const float* __restrict__ F,
    const float* __restrict__ sc, const float* __restrict__ sh,
    const float* __restrict__ wt, float* __restrict__ cv) {
  int gg = blockIdx.x, b = blockIdx.z, tid = threadIdx.x;
  int g = gg >> 1, half = gg & 1;
  int d = g - 4;
  bool flip = d > 0;
  int p = blockIdx.y * 256 + tid;
  int i = p / HH, j = p % HH;
  float acc[8];
  #pragma unroll
  for (int o = 0; o < 8; o++) acc[o] = 0.f;
  float raw[9], msk[9];
  bc_load(F, b, 0, 0, d, i, j, raw, msk);
  #pragma unroll 1
  for (int cu = 0; cu < 63; cu++) {
    int c = cu / 9, u = cu - c * 9;
    float cr[9], cm[9];
    #pragma unroll
    for (int v = 0; v < 9; v++) { cr[v] = raw[v]; cm[v] = msk[v]; }
    if (cu + 1 < 63) {
      int cn = (cu + 1) / 9, un = (cu + 1) - cn * 9;
      bc_load(F, b, cn, un, d, i, j, raw, msk);
    }
    float s = sc[c], h2 = sh[c];
    int uw = flip ? 8 - u : u;
    const float* wbase = wt + ((size_t)((g * 7 + c) * 81 + uw * 9)) * 16 + half * 8;
    #pragma unroll
    for (int v = 0; v < 9; v++) {
      float a = fmaxf(fmaf(cr[v], s, h2), 0.f) * cm[v];
      int vw = flip ? 8 - v : v;
      const float* wp = wbase + vw * 16;            // uniform -> s_load
      #pragma unroll
      for (int o = 0; o < 8; o++) acc[o] = fmaf(wp[o], a, acc[o]);
    }
  }
  size_t cvb = ((size_t)(b * 144 + g * 16 + half * 8)) * PLANE_A + p;
  #pragma unroll
  for (int o = 0; o < 8; o++) cv[cvb + o * PLANE_A] = acc[o];
}

// ===== depthwise 3x3: 4-row strips, block-uniform channel (SGPR weights) =====
// grid: BB*C*9 blocks; blk = (b*C + c)*9 + q. Stats: psum[c*18 + b*9 + q].
template<bool AFF>
__global__ __launch_bounds__(256) void k_dwconv(const float* __restrict__ in,
    const float* __restrict__ w, const float* __restrict__ isc, const float* __restrict__ ish,
    float* __restrict__ out, float* __restrict__ psum, float* __restrict__ psq, int C) {
  int blk = blockIdx.x, tid = threadIdx.x;
  int q = blk % 9; int rr = blk / 9; int c = rr % C; int b = rr / C;
  int widx = q * 256 + tid;
  int j = widx % HH, i0 = (widx / HH) * 4;
  float s  = AFF ? isc[c] : 1.f;                    // uniform -> s_load
  float h2 = AFF ? ish[c] : 0.f;
  const float* wc = w + c * 9;                      // uniform -> s_load
  const float* ip = in + ((size_t)(b * C + c)) * PLANE_A;
  int off[6][3]; float m[6][3];
  #pragma unroll
  for (int r6 = 0; r6 < 6; r6++) {
    int ii = i0 + r6 - 1;
    float mi = ((unsigned)ii < 96u) ? 1.f : 0.f;
    int iic = min(max(ii, 0), 95);
    #pragma unroll
    for (int dx = 0; dx < 3; dx++) {
      int jj = j + dx - 1;
      float mj = ((unsigned)jj < 96u) ? 1.f : 0.f;
      int jjc = min(max(jj, 0), 95);
      off[r6][dx] = iic * HH + jjc;
      m[r6][dx] = mi * mj;
    }
  }
  float win[6][3];
  #pragma unroll
  for (int r6 = 0; r6 < 6; r6++)
    #pragma unroll
    for (int dx = 0; dx < 3; dx++) {
      float vv = ip[off[r6][dx]];
      if (AFF) vv = fmaxf(fmaf(vv, s, h2), 0.f);
      win[r6][dx] = vv * m[r6][dx];
    }
  float acc[4];
  #pragma unroll
  for (int px = 0; px < 4; px++) acc[px] = 0.f;
  #pragma unroll
  for (int ky = 0; ky < 3; ky++)
    #pragma unroll
    for (int kx = 0; kx < 3; kx++) {
      float wv = wc[ky * 3 + kx];
      #pragma unroll
      for (int px = 0; px < 4; px++)
        acc[px] = fmaf(win[px + ky][kx], wv, acc[px]);
    }
  float* op = out + ((size_t)(b * C + c)) * PLANE_A + i0 * HH + j;
  #pragma unroll
  for (int px = 0; px < 4; px++) op[px * HH] = acc[px];
  float sv = acc[0] + acc[1] + acc[2] + acc[3];
  float qv = acc[0]*acc[0] + acc[1]*acc[1] + acc[2]*acc[2] + acc[3]*acc[3];
  #pragma unroll
  for (int off2 = 32; off2 > 0; off2 >>= 1) { sv += __shfl_down(sv, off2); qv += __shfl_down(qv, off2); }
  __shared__ float red[4][2];
  int wave = tid >> 6, lane = tid & 63;
  if (lane == 0) { red[wave][0] = sv; red[wave][1] = qv; }
  __syncthreads();
  if (tid == 0) {
    float S = red[0][0] + red[1][0] + red[2][0] + red[3][0];
    float Q = red[0][1] + red[1][1] + red[2][1] + red[3][1];
    psum[c * 18 + b * 9 + q] = S;
    psq [c * 18 + b * 9 + q] = Q;
  }
}

// ===== pointwise conv: 18 out/thread, transposed weights (contiguous s_load) =====
// grid (10, 72): x = output group (18 outputs), y = position block
// wpt layout: [c][o], row length 180. Stats: psum[o*72 + posblk].
template<int K>
__global__ __launch_bounds__(256) void k_pwconv(const float* __restrict__ in,
    const float* __restrict__ sc, const float* __restrict__ sh,
    const float* __restrict__ wpt, float* __restrict__ out,
    float* __restrict__ psum, float* __restrict__ psq) {
  int tid = threadIdx.x;
  int posblk = blockIdx.y;
  int p = posblk * 256 + tid;
  int b = p / PLANE_A, pp = p - b * PLANE_A;
  int obase = blockIdx.x * 18;
  float acc[18];
  #pragma unroll
  for (int o = 0; o < 18; o++) acc[o] = 0.f;
  const float* ib = in + (size_t)b * K * PLANE_A + pp;
  float xn[4];
  #pragma unroll
  for (int q2 = 0; q2 < 4; q2++) xn[q2] = ib[(size_t)q2 * PLANE_A];
  #pragma unroll 1
  for (int c0 = 0; c0 < K; c0 += 4) {
    float xv[4];
    #pragma unroll
    for (int q2 = 0; q2 < 4; q2++) xv[q2] = xn[q2];
    if (c0 + 4 < K) {
      #pragma unroll
      for (int q2 = 0; q2 < 4; q2++) xn[q2] = ib[(size_t)(c0 + 4 + q2) * PLANE_A];
    }
    #pragma unroll
    for (int q2 = 0; q2 < 4; q2++) {
      int c = c0 + q2;
      float v = fmaxf(fmaf(xv[q2], sc[c], sh[c]), 0.f);
      const float* wc = wpt + (size_t)c * 180 + obase;  // uniform, contiguous x18
      #pragma unroll
      for (int o = 0; o < 18; o++)
        acc[o] = fmaf(wc[o], v, acc[o]);
    }
  }
  #pragma unroll
  for (int o = 0; o < 18; o++)
    out[((size_t)(b * 180 + obase + o)) * PLANE_A + pp] = acc[o];
  __shared__ float rs[4][18], rq[4][18];
  int wave = tid >> 6, lane = tid & 63;
  #pragma unroll
  for (int o = 0; o < 18; o++) {
    float s = acc[o], q = acc[o] * acc[o];
    #pragma unroll
    for (int off = 32; off > 0; off >>= 1) { s += __shfl_down(s, off); q += __shfl_down(q, off); }
    if (lane == 0) { rs[wave][o] = s; rq[wave][o] = q; }
  }
  __syncthreads();
  if (tid < 18)
    psum[(obase + tid) * 72 + posblk] = rs[0][tid] + rs[1][tid] + rs[2][tid] + rs[3][tid];
  else if (tid < 36) {
    int o = tid - 18;
    psq[(obase + o) * 72 + posblk] = rq[0][o] + rq[1][o] + rq[2][o] + rq[3][o];
  }
}

// ===== final: 1x1 conv 180->9 (transposed wt) + softmax + expectation =====
__global__ __launch_bounds__(256) void k_final(const float* __restrict__ in,
    const float* __restrict__ sc, const float* __restrict__ sh,
    const float* __restrict__ wpt, float* __restrict__ out) {
  int tid = threadIdx.x;
  int t = blockIdx.x * 256 + tid;
  int b = t / PLANE_A, p = t - b * PLANE_A;
  const float* ib = in + (size_t)b * 180 * PLANE_A + p;
  float acc[9];
  #pragma unroll
  for (int o = 0; o < 9; o++) acc[o] = 0.f;
  float xn[4];
  #pragma unroll
  for (int q2 = 0; q2 < 4; q2++) xn[q2] = ib[(size_t)q2 * PLANE_A];
  #pragma unroll 1
  for (int c0 = 0; c0 < 180; c0 += 4) {
    float xv[4];
    #pragma unroll
    for (int q2 = 0; q2 < 4; q2++) xv[q2] = xn[q2];
    if (c0 + 4 < 180) {
      #pragma unroll
      for (int q2 = 0; q2 < 4; q2++) xn[q2] = ib[(size_t)(c0 + 4 + q2) * PLANE_A];
    }
    #pragma unroll
    for (int q2 = 0; q2 < 4; q2++) {
      int c = c0 + q2;
      float v = fmaxf(fmaf(xv[q2], sc[c], sh[c]), 0.f);
      const float* wc = wpt + (size_t)c * 9;        // uniform, contiguous x9
      #pragma unroll
      for (int o = 0; o < 9; o++) acc[o] = fmaf(wc[o], v, acc[o]);
    }
  }
  float m = acc[0];
  #pragma unroll
  for (int o = 1; o < 9; o++) m = fmaxf(m, acc[o]);
  float se = 0.f, num = 0.f;
  #pragma unroll
  for (int o = 0; o < 9; o++) {
    float e = expf(acc[o] - m);
    se += e;
    num += (float)(o - 4) * e;
  }
  out[t] = num / se;
}

extern "C" void kernel_launch(void* const* d_in, const int* in_sizes, int n_in,
                              void* d_out, int out_size, void* d_ws, size_t ws_size,
                              hipStream_t stream) {
  const float* x    = (const float*)d_in[0];
  const float* fw0  = (const float*)d_in[1];
  const float* fg0  = (const float*)d_in[2];
  const float* fb0  = (const float*)d_in[3];
  const float* fw   = (const float*)d_in[4];
  const float* fg   = (const float*)d_in[5];
  const float* fb   = (const float*)d_in[6];
  const float* bcw  = (const float*)d_in[7];
  const float* a0dw = (const float*)d_in[8];
  const float* a0dg = (const float*)d_in[9];
  const float* a0db = (const float*)d_in[10];
  const float* a0pw = (const float*)d_in[11];
  const float* a0pg = (const float*)d_in[12];
  const float* a0pb = (const float*)d_in[13];
  const float* amdw = (const float*)d_in[14];
  const float* amdg = (const float*)d_in[15];
  const float* amdb = (const float*)d_in[16];
  const float* ampw = (const float*)d_in[17];
  const float* ampg = (const float*)d_in[18];
  const float* ampb = (const float*)d_in[19];
  const float* ldw  = (const float*)d_in[20];
  const float* ldg  = (const float*)d_in[21];
  const float* ldb  = (const float*)d_in[22];
  const float* lpw  = (const float*)d_in[23];
  float* outp = (float*)d_out;

  float* FA    = (float*)d_ws;
  float* FB    = FA + (size_t)BB * 7 * PLANE_F;
  float* CV    = FB + (size_t)BB * 7 * PLANE_F;
  float* GA    = CV + (size_t)BB * 144 * PLANE_A;
  float* GB    = GA + (size_t)BB * 180 * PLANE_A;
  float* PSUM  = GB + (size_t)BB * 180 * PLANE_A;   // 7*1458 / 180*72 both fit
  float* PSQ   = PSUM + 180 * 288;
  float* SC    = PSQ + 180 * 288;
  float* SH    = SC + 180;
  float* WT    = SH + 180;                           // 81648
  float* WPT   = WT + 81648;                         // 157140
  float* WPT_A0 = WPT;                               // [144][180]
  float* WPT_AM = WPT + 25920;                       // 4 x [180][180]
  float* WPT_L  = WPT + 25920 + 129600;              // [180][9]

  const float invNbig = 1.0f / (float)(BB * PLANE_F);
  const float invNsmall = 1.0f / (float)(BB * PLANE_A);

  // weight prep (BuildCost shuffle + pointwise transposes), one dispatch
  k_wprep<<<(238788 + 255) / 256, 256, 0, stream>>>(bcw, a0pw, ampw, lpw, WT, WPT);

  // feature extraction (SAI layout, fp32), stats fused into conv blocks
  k_featconv0<<<NBLK_FEAT, 256, 0, stream>>>(x, fw0, FA, PSUM, PSQ);
  k_bnfinal<<<7, 256, 0, stream>>>(PSUM, PSQ, fg0, fb0, SC, SH, NBLK_FEAT, invNbig);

  float* cur = FA; float* nxt = FB;
  for (int i = 0; i < 6; i++) {
    k_featconv4<<<NBLK_FEAT, 256, 0, stream>>>(cur, fw + i * 441, SC, SH, nxt, PSUM, PSQ);
    k_bnfinal<<<7, 256, 0, stream>>>(PSUM, PSQ, fg + i * 7, fb + i * 7, SC, SH, NBLK_FEAT, invNbig);
    float* tmp = cur; cur = nxt; nxt = tmp;
  }

  // BuildCost (R6-proven structure: SGPR weights, branchless dist-1 prefetch)
  k_buildcost<<<dim3(18, 36, 2), 256, 0, stream>>>(cur, SC, SH, WT, CV);

  // aggregation: dwconv 4-row strips (SGPR weights), pwconv 18-out, fused stats
  k_dwconv<false><<<BB * 144 * 9, 256, 0, stream>>>(CV, a0dw, nullptr, nullptr, GA, PSUM, PSQ, 144);
  k_bnfinal<<<144, 256, 0, stream>>>(PSUM, PSQ, a0dg, a0db, SC, SH, 18, invNsmall);
  k_pwconv<144><<<dim3(10, 72), 256, 0, stream>>>(GA, SC, SH, WPT_A0, GB, PSUM, PSQ);
  k_bnfinal<<<180, 256, 0, stream>>>(PSUM, PSQ, a0pg, a0pb, SC, SH, 72, invNsmall);

  for (int m = 0; m < 4; m++) {
    k_dwconv<true><<<BB * 180 * 9, 256, 0, stream>>>(GB, amdw + m * 1620, SC, SH, GA, PSUM, PSQ, 180);
    k_bnfinal<<<180, 256, 0, stream>>>(PSUM, PSQ, amdg + m * 180, amdb + m * 180, SC, SH, 18, invNsmall);
    k_pwconv<180><<<dim3(10, 72), 256, 0, stream>>>(GA, SC, SH, WPT_AM + m * 32400, GB, PSUM, PSQ);
    k_bnfinal<<<180, 256, 0, stream>>>(PSUM, PSQ, ampg + m * 180, ampb + m * 180, SC, SH, 72, invNsmall);
  }

  k_dwconv<true><<<BB * 180 * 9, 256, 0, stream>>>(GB, ldw, SC, SH, GA, PSUM, PSQ, 180);
  k_bnfinal<<<180, 256, 0, stream>>>(PSUM, PSQ, ldg, ldb, SC, SH, 18, invNsmall);

  k_final<<<72, 256, 0, stream>>>(GA, SC, SH, WPT_L, outp);
}